// Round 6
// baseline (38.464 us; speedup 1.0000x reference)
//
#include <hip/hip_runtime.h>
#include <hip/hip_bf16.h>

#define TT 8192
#define DD 64
#define NTILE 64                        // 8192 / 128
#define NBLK (NTILE * (NTILE + 1) / 2)  // 2080 upper-tri tiles
#define TPB 4                           // tiles per block
#define NBLOCKS (NBLK / TPB)            // 520
#define NPREP 512                       // prep blocks (16 rows each)
#define L2E 1.4426950408889634f

typedef __attribute__((ext_vector_type(8))) short short8;
typedef __attribute__((ext_vector_type(4))) short short4v;
typedef __attribute__((ext_vector_type(4))) float f32x4;

static __device__ __forceinline__ float fast_exp2(float x) {
#if __has_builtin(__builtin_amdgcn_exp2f)
    return __builtin_amdgcn_exp2f(x);
#else
    float r; asm volatile("v_exp_f32 %0, %1" : "=v"(r) : "v"(x)); return r;
#endif
}

// ws layout:
//   [0]        float sq2[8192]        (L2E * ||x_i||^2)
//   [+32KB]    __hip_bfloat16 xb[8192][64]  (1 MB)
//   [+32KB+1MB]float p1[520]   term1 partials (weighted)
//   then       float p3[512]   term3 partials

__global__ __launch_bounds__(256) void prep_kernel(const float* __restrict__ x,
                                                   float* __restrict__ sq2,
                                                   short* __restrict__ xb,
                                                   float* __restrict__ p3) {
    const int tid = threadIdx.x;
    const int rloc = tid >> 4;
    const int lane16 = tid & 15;
    const int row = blockIdx.x * 16 + rloc;

    const float4 u = *(const float4*)(x + (size_t)row * DD + lane16 * 4);
    short4v s4;
    s4[0] = __builtin_bit_cast(short, __float2bfloat16(u.x));
    s4[1] = __builtin_bit_cast(short, __float2bfloat16(u.y));
    s4[2] = __builtin_bit_cast(short, __float2bfloat16(u.z));
    s4[3] = __builtin_bit_cast(short, __float2bfloat16(u.w));
    *(short4v*)(xb + (size_t)row * DD + lane16 * 4) = s4;

    float s = u.x*u.x + u.y*u.y + u.z*u.z + u.w*u.w;
    #pragma unroll
    for (int off = 1; off < 16; off <<= 1) s += __shfl_xor(s, off, 64);

    __shared__ float e3[16];
    if (lane16 == 0) {
        sq2[row] = L2E * s;
        e3[rloc] = __expf(s);
    }
    __syncthreads();
    if (tid == 0) {
        float t = 0.f;
        #pragma unroll
        for (int i = 0; i < 16; i++) t += e3[i];
        p3[blockIdx.x] = t;
    }
}

__global__ __launch_bounds__(256) void mmd_main(const short* __restrict__ xb,
                                                const float* __restrict__ sq2,
                                                float* __restrict__ p1) {
    const int k0 = blockIdx.x * TPB;
    // linear index -> upper-triangular (tr, tc), tr <= tc
    int tr = (int)((129.0f - sqrtf(16641.0f - 8.0f * (float)k0)) * 0.5f);
    while (tr * NTILE - tr * (tr - 1) / 2 > k0) --tr;
    while ((tr + 1) * NTILE - (tr + 1) * tr / 2 <= k0) ++tr;
    int tc = tr + (k0 - (tr * NTILE - tr * (tr - 1) / 2));

    const int wid  = threadIdx.x >> 6;
    const int lane = threadIdx.x & 63;
    const int wr = wid >> 1, wc = wid & 1;     // 2x2 wave grid, 64x64 per wave
    const int lrow = lane & 15;                // fragment row within 16
    const int kgrp = lane >> 4;                // k-group (8 contiguous bf16)
    const int crow0 = (lane >> 4) * 4;         // C/D: row=(lane>>4)*4+reg, col=lane&15
    const int ccol  = lane & 15;

    short8 A[2][4];              // [ks][m] row fragments (reused while tr fixed)
    short8 Ba[2][4], Bb[2][4];   // double-buffered col fragments
    float  sqrl[16];
    float  sqca[4], sqcb[4];
    float  local = 0.f;

#define LOAD_A(TRR)                                                                   \
    { _Pragma("unroll")                                                               \
      for (int ks = 0; ks < 2; ks++) {                                                \
          const int koff = ks * 32 + kgrp * 8;                                        \
          _Pragma("unroll")                                                           \
          for (int m = 0; m < 4; m++)                                                 \
              A[ks][m] = *(const short8*)(xb +                                        \
                  (size_t)((TRR) * 128 + wr * 64 + m * 16 + lrow) * DD + koff);       \
      } }

#define LOAD_SQR(TRR)                                                                 \
    { _Pragma("unroll")                                                               \
      for (int m = 0; m < 4; m++) {                                                   \
          const float4 f = *(const float4*)(sq2 + (TRR) * 128 + wr * 64 + m * 16 + crow0); \
          sqrl[4*m+0] = f.x; sqrl[4*m+1] = f.y; sqrl[4*m+2] = f.z; sqrl[4*m+3] = f.w; \
      } }

#define LOAD_B(BUF, SQC, TCC)                                                         \
    { _Pragma("unroll")                                                               \
      for (int ks = 0; ks < 2; ks++) {                                                \
          const int koff = ks * 32 + kgrp * 8;                                        \
          _Pragma("unroll")                                                           \
          for (int n = 0; n < 4; n++)                                                 \
              BUF[ks][n] = *(const short8*)(xb +                                      \
                  (size_t)((TCC) * 128 + wc * 64 + n * 16 + lrow) * DD + koff);       \
      }                                                                               \
      _Pragma("unroll")                                                               \
      for (int n = 0; n < 4; n++)                                                     \
          SQC[n] = sq2[(TCC) * 128 + wc * 64 + n * 16 + ccol]; }

    LOAD_A(tr);
    LOAD_SQR(tr);
    LOAD_B(Ba, sqca, tc);

    #pragma unroll
    for (int t = 0; t < TPB; t++) {
        f32x4 c[4][4];
        #pragma unroll
        for (int m = 0; m < 4; m++)
            #pragma unroll
            for (int n = 0; n < 4; n++)
                c[m][n] = (f32x4){0.f, 0.f, 0.f, 0.f};

        // MFMA on the current B buffer (static selection after unroll)
        #pragma unroll
        for (int ks = 0; ks < 2; ks++)
            #pragma unroll
            for (int m = 0; m < 4; m++)
                #pragma unroll
                for (int n = 0; n < 4; n++)
                    c[m][n] = __builtin_amdgcn_mfma_f32_16x16x32_bf16(
                        A[ks][m], (t & 1) ? Bb[ks][n] : Ba[ks][n], c[m][n], 0, 0, 0);

        // next tile coords; issue next loads BEFORE the epilogue (latency cover)
        int trn = tr, tcn = tc + 1;
        if (tcn == NTILE) { trn = tr + 1; tcn = trn; }
        const bool rowch = (trn != tr);
        if (t < TPB - 1) {
            if (rowch) LOAD_A(trn);
            if (t & 1) { LOAD_B(Ba, sqca, tcn); }
            else       { LOAD_B(Bb, sqcb, tcn); }
        }

        // epilogue: sum exp2(L2E*(sq_r + sq_c - 2 g))
        const float w = (tr == tc) ? 1.0f : 2.0f;
        float acc4[4] = {0.f, 0.f, 0.f, 0.f};
        #pragma unroll
        for (int n = 0; n < 4; n++) {
            const float sc = (t & 1) ? sqcb[n] : sqca[n];
            #pragma unroll
            for (int m = 0; m < 4; m++)
                #pragma unroll
                for (int r = 0; r < 4; r++)
                    acc4[r] += fast_exp2(fmaf(-2.0f * L2E, c[m][n][r], sqrl[m * 4 + r] + sc));
        }
        local += ((acc4[0] + acc4[1]) + (acc4[2] + acc4[3])) * w;

        if (t < TPB - 1 && rowch) LOAD_SQR(trn);
        tr = trn; tc = tcn;
    }
#undef LOAD_A
#undef LOAD_SQR
#undef LOAD_B

    #pragma unroll
    for (int off = 32; off; off >>= 1) local += __shfl_down(local, off, 64);
    __shared__ float red[4];
    if (lane == 0) red[wid] = local;
    __syncthreads();
    if (threadIdx.x == 0)
        p1[blockIdx.x] = red[0] + red[1] + red[2] + red[3];
}

__global__ void finalize_kernel(const float* __restrict__ p1, const float* __restrict__ p3,
                                float* __restrict__ out) {
    const int lane = threadIdx.x & 63;
    const int wid  = threadIdx.x >> 6;
    float s1 = 0.f, s3 = 0.f;
    for (int i = threadIdx.x; i < NBLOCKS; i += 256) s1 += p1[i];
    for (int i = threadIdx.x; i < NPREP; i += 256) s3 += p3[i];
    #pragma unroll
    for (int off = 32; off; off >>= 1) {
        s1 += __shfl_down(s1, off, 64);
        s3 += __shfl_down(s3, off, 64);
    }
    __shared__ float r1[4], r3[4];
    if (lane == 0) { r1[wid] = s1; r3[wid] = s3; }
    __syncthreads();
    if (threadIdx.x == 0) {
        const float t1 = (r1[0] + r1[1] + r1[2] + r1[3]) / ((float)TT * (float)TT);
        const float t3 = (r3[0] + r3[1] + r3[2] + r3[3]) / (float)TT;
        out[0] = t1 + 1.0f + t3;
    }
}

extern "C" void kernel_launch(void* const* d_in, const int* in_sizes, int n_in,
                              void* d_out, int out_size, void* d_ws, size_t ws_size,
                              hipStream_t stream) {
    const float* x = (const float*)d_in[0];   // xs: [4, 8192, 64] f32; only batch 0 used
    float* out = (float*)d_out;
    char* ws = (char*)d_ws;

    float* sq2 = (float*)ws;
    short* xb = (short*)(ws + TT * sizeof(float));
    float* p1 = (float*)(ws + TT * sizeof(float) + (size_t)TT * DD * sizeof(short));
    float* p3 = p1 + NBLOCKS;

    prep_kernel<<<NPREP, 256, 0, stream>>>(x, sq2, xb, p3);
    mmd_main<<<NBLOCKS, 256, 0, stream>>>(xb, sq2, p1);
    finalize_kernel<<<1, 256, 0, stream>>>(p1, p3, out);
}